// Round 6
// baseline (871.039 us; speedup 1.0000x reference)
//
#include <hip/hip_runtime.h>

#define NN 40000
#define NE 640000
#define NSB ((NN + 255) / 256)  // 157 scan blocks

static __device__ __forceinline__ float lrelu(float x) { return x > 0.0f ? x : 0.2f * x; }

static __device__ __forceinline__ float wave_max(float v) {
    for (int off = 32; off; off >>= 1) v = fmaxf(v, __shfl_xor(v, off));
    return v;
}
static __device__ __forceinline__ float wave_sum(float v) {
    for (int off = 32; off; off >>= 1) v += __shfl_xor(v, off);
    return v;
}

// ---------------- tiled GEMM: Y[r][c] = sum_k X[r][k] * W[k][c] ----------------
template <int FIN, int FOUT>
__global__ __launch_bounds__(256) void k_gemm_t(const float* __restrict__ X,
                                                const float* __restrict__ W,
                                                float* __restrict__ Y) {
    constexpr int XLD = FIN + 4;
    __shared__ float ws[FIN * 64];
    __shared__ float xs[64 * XLD];
    const int t = threadIdx.x;
    const int row0 = blockIdx.x * 64;
    const int col0 = blockIdx.y * 64;

    for (int i = t; i < FIN * 16; i += 256) {
        int k = i >> 4, cc = (i & 15) << 2;
        *(float4*)&ws[k * 64 + cc] = *(const float4*)&W[k * FOUT + col0 + cc];
    }
    for (int i = t; i < 64 * (FIN / 4); i += 256) {
        int r = i / (FIN / 4), kk = (i % (FIN / 4)) << 2;
        *(float4*)&xs[r * XLD + kk] = *(const float4*)&X[(size_t)(row0 + r) * FIN + kk];
    }
    __syncthreads();

    const int c0 = (t & 15) << 2;
    const int r0 = (t >> 4) << 2;
    float acc[4][4] = {};
#pragma unroll 2
    for (int k = 0; k < FIN; k += 4) {
        float4 xv[4], wv[4];
#pragma unroll
        for (int i = 0; i < 4; ++i) xv[i] = *(const float4*)&xs[(r0 + i) * XLD + k];
#pragma unroll
        for (int j = 0; j < 4; ++j) wv[j] = *(const float4*)&ws[(k + j) * 64 + c0];
#pragma unroll
        for (int i = 0; i < 4; ++i) {
            acc[i][0] = fmaf(xv[i].x, wv[0].x, acc[i][0]);
            acc[i][1] = fmaf(xv[i].x, wv[0].y, acc[i][1]);
            acc[i][2] = fmaf(xv[i].x, wv[0].z, acc[i][2]);
            acc[i][3] = fmaf(xv[i].x, wv[0].w, acc[i][3]);
            acc[i][0] = fmaf(xv[i].y, wv[1].x, acc[i][0]);
            acc[i][1] = fmaf(xv[i].y, wv[1].y, acc[i][1]);
            acc[i][2] = fmaf(xv[i].y, wv[1].z, acc[i][2]);
            acc[i][3] = fmaf(xv[i].y, wv[1].w, acc[i][3]);
            acc[i][0] = fmaf(xv[i].z, wv[2].x, acc[i][0]);
            acc[i][1] = fmaf(xv[i].z, wv[2].y, acc[i][1]);
            acc[i][2] = fmaf(xv[i].z, wv[2].z, acc[i][2]);
            acc[i][3] = fmaf(xv[i].z, wv[2].w, acc[i][3]);
            acc[i][0] = fmaf(xv[i].w, wv[3].x, acc[i][0]);
            acc[i][1] = fmaf(xv[i].w, wv[3].y, acc[i][1]);
            acc[i][2] = fmaf(xv[i].w, wv[3].z, acc[i][2]);
            acc[i][3] = fmaf(xv[i].w, wv[3].w, acc[i][3]);
        }
    }
#pragma unroll
    for (int i = 0; i < 4; ++i) {
        float4 v = make_float4(acc[i][0], acc[i][1], acc[i][2], acc[i][3]);
        *(float4*)&Y[(size_t)(row0 + r0 + i) * FOUT + col0 + c0] = v;
    }
}

// ---------------- CSR build ----------------
__global__ void k_zero_int(int* __restrict__ p, int n) {
    int i = blockIdx.x * blockDim.x + threadIdx.x;
    if (i < n) p[i] = 0;
}
__global__ void k_count(const int* __restrict__ dst, int* __restrict__ cnt) {
    int e = blockIdx.x * blockDim.x + threadIdx.x;
    if (e < NE) atomicAdd(&cnt[dst[e]], 1);
}
__global__ void k_bsum(const int* __restrict__ cnt, int* __restrict__ bsum) {
    __shared__ int wsums[4];
    int i = blockIdx.x * 256 + threadIdx.x;
    int v = (i < NN) ? cnt[i] : 0;
    for (int off = 32; off; off >>= 1) v += __shfl_down(v, off);
    if ((threadIdx.x & 63) == 0) wsums[threadIdx.x >> 6] = v;
    __syncthreads();
    if (threadIdx.x == 0) bsum[blockIdx.x] = wsums[0] + wsums[1] + wsums[2] + wsums[3];
}
__global__ void k_scanpart(const int* __restrict__ bsum, int* __restrict__ bofs,
                           int* __restrict__ rowptr) {
    __shared__ int s[256];
    int t = threadIdx.x;
    int v = (t < NSB) ? bsum[t] : 0;
    s[t] = v;
    __syncthreads();
    for (int off = 1; off < 256; off <<= 1) {
        int u = (t >= off) ? s[t - off] : 0;
        __syncthreads();
        s[t] += u;
        __syncthreads();
    }
    if (t < NSB) bofs[t] = s[t] - v;
    if (t == 0) rowptr[NN] = NE;
}
__global__ void k_scatter(const int* __restrict__ cnt, const int* __restrict__ bofs,
                          int* __restrict__ rowptr, int* __restrict__ cursor) {
    __shared__ int wsums[4];
    int t = threadIdx.x;
    int lane = t & 63, w = t >> 6;
    int i = blockIdx.x * 256 + t;
    int v = (i < NN) ? cnt[i] : 0;
    int x = v;
    for (int off = 1; off < 64; off <<= 1) {
        int u = __shfl_up(x, off);
        if (lane >= off) x += u;
    }
    if (lane == 63) wsums[w] = x;
    __syncthreads();
    int wofs = 0;
    for (int k = 0; k < w; ++k) wofs += wsums[k];
    int excl = bofs[blockIdx.x] + wofs + x - v;
    if (i < NN) {
        rowptr[i] = excl;
        cursor[i] = excl;
    }
}
__global__ void k_fill(const int* __restrict__ src, const int* __restrict__ dst,
                       int* __restrict__ cursor, int* __restrict__ csr_src) {
    int e = blockIdx.x * blockDim.x + threadIdx.x;
    if (e < NE) {
        int p = atomicAdd(&cursor[dst[e]], 1);
        csr_src[p] = src[e];
    }
}
__global__ void k_dinv(const int* __restrict__ rowptr, float* __restrict__ dinv) {
    int i = blockIdx.x * blockDim.x + threadIdx.x;
    if (i < NN) dinv[i] = rsqrtf(1.0f + (float)(rowptr[i + 1] - rowptr[i]));
}

// ---------------- per-edge weight precompute ----------------
// GCN: ew[e] = dinv[src]*dinv[dst], sw[d] = dinv[d]^2   (graph-only, reused by layers 1&3)
__global__ __launch_bounds__(256) void k_weights_gcn(const int* __restrict__ rowptr,
                                                     const int* __restrict__ csr_src,
                                                     const float* __restrict__ dinv,
                                                     float* __restrict__ ew,
                                                     float* __restrict__ sw) {
    int node = blockIdx.x * 4 + (threadIdx.x >> 6);
    int lane = threadIdx.x & 63;
    if (node >= NN) return;
    int beg = rowptr[node], end = rowptr[node + 1];
    float dd = dinv[node];
    for (int j = beg + lane; j < end; j += 64) ew[j] = dinv[csr_src[j]] * dd;
    if (lane == 0) sw[node] = dd * dd;
}

// GAT: single-pass wave softmax -> ew[e] = alpha_e, sw[d] = alpha_self
__global__ __launch_bounds__(256) void k_weights_gat(const int* __restrict__ rowptr,
                                                     const int* __restrict__ csr_src,
                                                     const float* __restrict__ asrc,
                                                     const float* __restrict__ adst,
                                                     float* __restrict__ ew,
                                                     float* __restrict__ sw) {
    int node = blockIdx.x * 4 + (threadIdx.x >> 6);
    int lane = threadIdx.x & 63;
    if (node >= NN) return;
    int beg = rowptr[node], end = rowptr[node + 1];
    int deg = end - beg;
    float ad = adst[node];
    float slog = lrelu(asrc[node] + ad);

    if (deg <= 64) {
        float logit = -1e30f;
        if (lane < deg) logit = lrelu(asrc[csr_src[beg + lane]] + ad);
        float m = fmaxf(slog, wave_max(logit));
        float e = (lane < deg) ? __expf(logit - m) : 0.0f;
        float z = wave_sum(e) + __expf(slog - m);
        float zi = 1.0f / z;
        if (lane < deg) ew[beg + lane] = e * zi;
        if (lane == 0) sw[node] = __expf(slog - m) * zi;
    } else {
        float lm = slog;
        for (int j = beg + lane; j < end; j += 64) lm = fmaxf(lm, lrelu(asrc[csr_src[j]] + ad));
        float m = wave_max(lm);
        float lz = 0.0f;
        for (int j = beg + lane; j < end; j += 64)
            lz += __expf(lrelu(asrc[csr_src[j]] + ad) - m);
        float z = wave_sum(lz) + __expf(slog - m);
        float zi = 1.0f / z;
        for (int j = beg + lane; j < end; j += 64)
            ew[j] = __expf(lrelu(asrc[csr_src[j]] + ad) - m) * zi;
        if (lane == 0) sw[node] = __expf(slog - m) * zi;
    }
}

// ---------------- channel-sliced XCD-affine aggregation ----------------
// slice = blockIdx.x & (NSLICE-1): default round-robin block->XCD dispatch keeps each
// 16-channel feature slice (2.56 MB) resident in one XCD's 4 MB L2 (perf-only assumption).
// Wave layout: lane = e4*16 + c -> 4 edges x 16 channels. csr_src/ew streamed nontemporal.
template <int F, int NSLICE, bool RELU>
__global__ __launch_bounds__(256) void k_agg_slice(const int* __restrict__ rowptr,
                                                   const int* __restrict__ csr_src,
                                                   const float* __restrict__ ew,
                                                   const float* __restrict__ sw,
                                                   const float* __restrict__ h,
                                                   const float* __restrict__ b,
                                                   float* __restrict__ out) {
    const int slice = blockIdx.x & (NSLICE - 1);
    const int nb = blockIdx.x / NSLICE;
    const int node = nb * 4 + (threadIdx.x >> 6);
    const int lane = threadIdx.x & 63;
    const int c = lane & 15;
    const int e4 = lane >> 4;
    const int col = slice * 16 + c;

    int beg = rowptr[node], end = rowptr[node + 1];
    float acc = 0.0f;
    for (int g = beg; g < end; g += 4) {
        int e = g + e4;
        int s = node;
        float w = 0.0f;
        if (e < end) {
            s = __builtin_nontemporal_load(&csr_src[e]);
            w = __builtin_nontemporal_load(&ew[e]);
        }
        acc = fmaf(w, h[(size_t)s * F + col], acc);
    }
    // reduce across the 4 edge groups (lanes c, c+16, c+32, c+48)
    acc += __shfl_xor(acc, 16);
    acc += __shfl_xor(acc, 32);

    if (lane < 16) {
        float r = fmaf(sw[node], h[(size_t)node * F + col], acc) + b[col];
        if (RELU) r = fmaxf(r, 0.0f);
        __builtin_nontemporal_store(r, &out[(size_t)node * F + col]);
    }
}

// ---------------- GAT per-node attention scalars ----------------
__global__ void k_gat_scalars(const float* __restrict__ hg, const float* __restrict__ a_s,
                              const float* __restrict__ a_d, float* __restrict__ asrc,
                              float* __restrict__ adst, int F) {
    int node = blockIdx.x * (blockDim.x >> 6) + (threadIdx.x >> 6);
    int lane = threadIdx.x & 63;
    if (node >= NN) return;
    float s = 0.0f, d = 0.0f;
    for (int c = lane; c < F; c += 64) {
        float v = hg[(size_t)node * F + c];
        s += v * a_s[c];
        d += v * a_d[c];
    }
    for (int off = 32; off; off >>= 1) {
        s += __shfl_down(s, off);
        d += __shfl_down(d, off);
    }
    if (lane == 0) {
        asrc[node] = s;
        adst[node] = d;
    }
}

extern "C" void kernel_launch(void* const* d_in, const int* in_sizes, int n_in,
                              void* d_out, int out_size, void* d_ws, size_t ws_size,
                              hipStream_t stream) {
    const float* x = (const float*)d_in[0];
    const int* src = (const int*)d_in[1];
    const int* dst = src + NE;
    const float* W1 = (const float*)d_in[2];
    const float* b1 = (const float*)d_in[3];
    const float* Wg1 = (const float*)d_in[4];
    const float* ag1s = (const float*)d_in[5];
    const float* ag1d = (const float*)d_in[6];
    const float* bg1 = (const float*)d_in[7];
    const float* W2 = (const float*)d_in[8];
    const float* b2 = (const float*)d_in[9];
    const float* Wg2 = (const float*)d_in[10];
    const float* ag2s = (const float*)d_in[11];
    const float* ag2d = (const float*)d_in[12];
    const float* bg2 = (const float*)d_in[13];

    float* enc = (float*)d_out;             // [NN,128]
    float* dec = enc + (size_t)NN * 128;    // [NN,64]

    float* ws = (float*)d_ws;
    float* bufA = ws;                       // NN*128
    float* bufB = bufA + (size_t)NN * 128;  // NN*128
    float* dinv = bufB + (size_t)NN * 128;  // NN
    float* asrc = dinv + NN;                // NN
    float* adst = asrc + NN;                // NN
    float* swg = adst + NN;                 // NN (GCN self weights)
    float* swa = swg + NN;                  // NN (GAT self weights)
    float* ewg = swa + NN;                  // NE (GCN edge weights)
    float* ewa = ewg + NE;                  // NE (GAT edge weights)
    int* cnt = (int*)(ewa + NE);            // NN
    int* rowptr = cnt + NN;                 // NN+1
    int* cursor = rowptr + NN + 1;          // NN
    int* csr_src = cursor + NN;             // NE
    int* bsum = csr_src + NE;               // NSB
    int* bofs = bsum + NSB;                 // NSB

    const int TB = 256;
    int gN = (NN + TB - 1) / TB;
    int gE = (NE + TB - 1) / TB;
    int gScal = (NN + 3) / 4;
    int gWave = (NN + 3) / 4;  // 10000 blocks, 4 waves each = 1 wave/node
    int gS8 = gWave * 8;       // sliced agg grid, F=128
    int gS4 = gWave * 4;       // sliced agg grid, F=64

    // ---- CSR build ----
    k_zero_int<<<gN, TB, 0, stream>>>(cnt, NN);
    k_count<<<gE, TB, 0, stream>>>(dst, cnt);
    k_bsum<<<NSB, 256, 0, stream>>>(cnt, bsum);
    k_scanpart<<<1, 256, 0, stream>>>(bsum, bofs, rowptr);
    k_scatter<<<NSB, 256, 0, stream>>>(cnt, bofs, rowptr, cursor);
    k_fill<<<gE, TB, 0, stream>>>(src, dst, cursor, csr_src);
    k_dinv<<<gN, TB, 0, stream>>>(rowptr, dinv);
    k_weights_gcn<<<gWave, TB, 0, stream>>>(rowptr, csr_src, dinv, ewg, swg);

    // ---- Layer 1: GCN 128->128 + ReLU -> bufB ----
    k_gemm_t<128, 128><<<dim3(NN / 64, 2), 256, 0, stream>>>(x, W1, bufA);
    k_agg_slice<128, 8, true><<<gS8, TB, 0, stream>>>(rowptr, csr_src, ewg, swg, bufA, b1, bufB);

    // ---- Layer 2: GAT 128->128 -> encoded ----
    k_gemm_t<128, 128><<<dim3(NN / 64, 2), 256, 0, stream>>>(bufB, Wg1, bufA);
    k_gat_scalars<<<gScal, TB, 0, stream>>>(bufA, ag1s, ag1d, asrc, adst, 128);
    k_weights_gat<<<gWave, TB, 0, stream>>>(rowptr, csr_src, asrc, adst, ewa, swa);
    k_agg_slice<128, 8, false><<<gS8, TB, 0, stream>>>(rowptr, csr_src, ewa, swa, bufA, bg1, enc);

    // ---- Layer 3: GCN 128->64 + ReLU -> bufB ----
    k_gemm_t<128, 64><<<dim3(NN / 64, 1), 256, 0, stream>>>(enc, W2, bufA);
    k_agg_slice<64, 4, true><<<gS4, TB, 0, stream>>>(rowptr, csr_src, ewg, swg, bufA, b2, bufB);

    // ---- Layer 4: GAT 64->64 -> decoded ----
    k_gemm_t<64, 64><<<dim3(NN / 64, 1), 256, 0, stream>>>(bufB, Wg2, bufA);
    k_gat_scalars<<<gScal, TB, 0, stream>>>(bufA, ag2s, ag2d, asrc, adst, 64);
    k_weights_gat<<<gWave, TB, 0, stream>>>(rowptr, csr_src, asrc, adst, ewa, swa);
    k_agg_slice<64, 4, false><<<gS4, TB, 0, stream>>>(rowptr, csr_src, ewa, swa, bufA, bg2, dec);
}

// Round 7
// 264.101 us; speedup vs baseline: 3.2981x; 3.2981x over previous
//
#include <hip/hip_runtime.h>

#define NN 40000
#define NE 640000
#define NSB ((NN + 255) / 256)  // 157 scan blocks

typedef unsigned int uint32;

static __device__ __forceinline__ float lrelu(float x) { return x > 0.0f ? x : 0.2f * x; }

static __device__ __forceinline__ float wave_max(float v) {
    for (int off = 32; off; off >>= 1) v = fmaxf(v, __shfl_xor(v, off));
    return v;
}
static __device__ __forceinline__ float wave_sum(float v) {
    for (int off = 32; off; off >>= 1) v += __shfl_xor(v, off);
    return v;
}

// bf16 RNE pack/unpack helpers (packed uint = [ch0 | ch1<<16])
static __device__ __forceinline__ uint32 bfr(float x) {
    uint32 u = __float_as_uint(x);
    return u + 0x7FFFu + ((u >> 16) & 1u);
}
static __device__ __forceinline__ uint32 pack2(float a, float b) {
    return (bfr(a) >> 16) | (bfr(b) & 0xFFFF0000u);
}
static __device__ __forceinline__ float lo16(uint32 v) { return __uint_as_float(v << 16); }
static __device__ __forceinline__ float hi16(uint32 v) { return __uint_as_float(v & 0xFFFF0000u); }

// ---------------- tiled GEMM: Y = X*W, dual fp32 + bf16 outputs ----------------
template <int FIN, int FOUT>
__global__ __launch_bounds__(256) void k_gemm_t(const float* __restrict__ X,
                                                const float* __restrict__ W,
                                                float* __restrict__ Y,
                                                uint32* __restrict__ Y16) {
    constexpr int XLD = FIN + 4;
    __shared__ float ws[FIN * 64];
    __shared__ float xs[64 * XLD];
    const int t = threadIdx.x;
    const int row0 = blockIdx.x * 64;
    const int col0 = blockIdx.y * 64;

    for (int i = t; i < FIN * 16; i += 256) {
        int k = i >> 4, cc = (i & 15) << 2;
        *(float4*)&ws[k * 64 + cc] = *(const float4*)&W[k * FOUT + col0 + cc];
    }
    for (int i = t; i < 64 * (FIN / 4); i += 256) {
        int r = i / (FIN / 4), kk = (i % (FIN / 4)) << 2;
        *(float4*)&xs[r * XLD + kk] = *(const float4*)&X[(size_t)(row0 + r) * FIN + kk];
    }
    __syncthreads();

    const int c0 = (t & 15) << 2;
    const int r0 = (t >> 4) << 2;
    float acc[4][4] = {};
#pragma unroll 2
    for (int k = 0; k < FIN; k += 4) {
        float4 xv[4], wv[4];
#pragma unroll
        for (int i = 0; i < 4; ++i) xv[i] = *(const float4*)&xs[(r0 + i) * XLD + k];
#pragma unroll
        for (int j = 0; j < 4; ++j) wv[j] = *(const float4*)&ws[(k + j) * 64 + c0];
#pragma unroll
        for (int i = 0; i < 4; ++i) {
            acc[i][0] = fmaf(xv[i].x, wv[0].x, acc[i][0]);
            acc[i][1] = fmaf(xv[i].x, wv[0].y, acc[i][1]);
            acc[i][2] = fmaf(xv[i].x, wv[0].z, acc[i][2]);
            acc[i][3] = fmaf(xv[i].x, wv[0].w, acc[i][3]);
            acc[i][0] = fmaf(xv[i].y, wv[1].x, acc[i][0]);
            acc[i][1] = fmaf(xv[i].y, wv[1].y, acc[i][1]);
            acc[i][2] = fmaf(xv[i].y, wv[1].z, acc[i][2]);
            acc[i][3] = fmaf(xv[i].y, wv[1].w, acc[i][3]);
            acc[i][0] = fmaf(xv[i].z, wv[2].x, acc[i][0]);
            acc[i][1] = fmaf(xv[i].z, wv[2].y, acc[i][1]);
            acc[i][2] = fmaf(xv[i].z, wv[2].z, acc[i][2]);
            acc[i][3] = fmaf(xv[i].z, wv[2].w, acc[i][3]);
            acc[i][0] = fmaf(xv[i].w, wv[3].x, acc[i][0]);
            acc[i][1] = fmaf(xv[i].w, wv[3].y, acc[i][1]);
            acc[i][2] = fmaf(xv[i].w, wv[3].z, acc[i][2]);
            acc[i][3] = fmaf(xv[i].w, wv[3].w, acc[i][3]);
        }
    }
#pragma unroll
    for (int i = 0; i < 4; ++i) {
        float4 v = make_float4(acc[i][0], acc[i][1], acc[i][2], acc[i][3]);
        size_t base = (size_t)(row0 + r0 + i) * FOUT + col0 + c0;
        *(float4*)&Y[base] = v;
        uint2 p = make_uint2(pack2(v.x, v.y), pack2(v.z, v.w));
        *(uint2*)&Y16[base >> 1] = p;
    }
}

// ---------------- CSR build ----------------
__global__ void k_zero_int(int* __restrict__ p, int n) {
    int i = blockIdx.x * blockDim.x + threadIdx.x;
    if (i < n) p[i] = 0;
}
__global__ void k_count(const int* __restrict__ dst, int* __restrict__ cnt) {
    int e = blockIdx.x * blockDim.x + threadIdx.x;
    if (e < NE) atomicAdd(&cnt[dst[e]], 1);
}
__global__ void k_bsum(const int* __restrict__ cnt, int* __restrict__ bsum) {
    __shared__ int wsums[4];
    int i = blockIdx.x * 256 + threadIdx.x;
    int v = (i < NN) ? cnt[i] : 0;
    for (int off = 32; off; off >>= 1) v += __shfl_down(v, off);
    if ((threadIdx.x & 63) == 0) wsums[threadIdx.x >> 6] = v;
    __syncthreads();
    if (threadIdx.x == 0) bsum[blockIdx.x] = wsums[0] + wsums[1] + wsums[2] + wsums[3];
}
__global__ void k_scanpart(const int* __restrict__ bsum, int* __restrict__ bofs,
                           int* __restrict__ rowptr) {
    __shared__ int s[256];
    int t = threadIdx.x;
    int v = (t < NSB) ? bsum[t] : 0;
    s[t] = v;
    __syncthreads();
    for (int off = 1; off < 256; off <<= 1) {
        int u = (t >= off) ? s[t - off] : 0;
        __syncthreads();
        s[t] += u;
        __syncthreads();
    }
    if (t < NSB) bofs[t] = s[t] - v;
    if (t == 0) rowptr[NN] = NE;
}
__global__ void k_scatter(const int* __restrict__ cnt, const int* __restrict__ bofs,
                          int* __restrict__ rowptr, int* __restrict__ cursor) {
    __shared__ int wsums[4];
    int t = threadIdx.x;
    int lane = t & 63, w = t >> 6;
    int i = blockIdx.x * 256 + t;
    int v = (i < NN) ? cnt[i] : 0;
    int x = v;
    for (int off = 1; off < 64; off <<= 1) {
        int u = __shfl_up(x, off);
        if (lane >= off) x += u;
    }
    if (lane == 63) wsums[w] = x;
    __syncthreads();
    int wofs = 0;
    for (int k = 0; k < w; ++k) wofs += wsums[k];
    int excl = bofs[blockIdx.x] + wofs + x - v;
    if (i < NN) {
        rowptr[i] = excl;
        cursor[i] = excl;
    }
}
__global__ void k_fill(const int* __restrict__ src, const int* __restrict__ dst,
                       int* __restrict__ cursor, int* __restrict__ csr_src) {
    int e = blockIdx.x * blockDim.x + threadIdx.x;
    if (e < NE) {
        int p = atomicAdd(&cursor[dst[e]], 1);
        csr_src[p] = src[e];
    }
}
__global__ void k_dinv(const int* __restrict__ rowptr, float* __restrict__ dinv) {
    int i = blockIdx.x * blockDim.x + threadIdx.x;
    if (i < NN) dinv[i] = rsqrtf(1.0f + (float)(rowptr[i + 1] - rowptr[i]));
}

// ---- bf16 gather steps: 8 independent loads in flight, fp32 accumulate ----
// F=128: whole wave per edge; lane owns channels (2*lane, 2*lane+1); 256B/edge row.
static __device__ __forceinline__ void gath128(const uint32* __restrict__ h16, int lane, int myi,
                                               float myw, int cnt, float* acc) {
    for (int j = 0; j < cnt; j += 8) {
        int s[8];
        float w[8];
#pragma unroll
        for (int u = 0; u < 8; ++u) {
            s[u] = __shfl(myi, j + u);
            w[u] = __shfl(myw, j + u);
        }
        uint32 v[8];
#pragma unroll
        for (int u = 0; u < 8; ++u) v[u] = h16[(size_t)s[u] * 64 + lane];
#pragma unroll
        for (int u = 0; u < 8; ++u) {
            acc[0] = fmaf(w[u], lo16(v[u]), acc[0]);
            acc[1] = fmaf(w[u], hi16(v[u]), acc[1]);
        }
    }
}
// F=64: half-wave per edge (2 edges/step); lane owns channels (2*(lane&31)+q); 128B/edge row.
static __device__ __forceinline__ void gath64(const uint32* __restrict__ h16, int lane, int myi,
                                              float myw, int cnt, float* acc) {
    int hh = lane >> 5, cl = lane & 31;
    for (int j = 0; j < cnt; j += 16) {
        int s[8];
        float w[8];
#pragma unroll
        for (int u = 0; u < 8; ++u) {
            int e = j + 2 * u + hh;
            s[u] = __shfl(myi, e);
            w[u] = __shfl(myw, e);
        }
        uint32 v[8];
#pragma unroll
        for (int u = 0; u < 8; ++u) v[u] = h16[(size_t)s[u] * 32 + cl];
#pragma unroll
        for (int u = 0; u < 8; ++u) {
            acc[0] = fmaf(w[u], lo16(v[u]), acc[0]);
            acc[1] = fmaf(w[u], hi16(v[u]), acc[1]);
        }
    }
}

// ---------------- GCN gather: one wave per node, bf16 source ----------------
template <int F>
__global__ __launch_bounds__(256) void k_gcn_gather_w(const int* __restrict__ rowptr,
                                                      const int* __restrict__ csr_src,
                                                      const uint32* __restrict__ h16,
                                                      const float* __restrict__ dinv,
                                                      const float* __restrict__ b,
                                                      float* __restrict__ out) {
    int node = blockIdx.x * 4 + (threadIdx.x >> 6);
    int lane = threadIdx.x & 63;
    int beg = rowptr[node], end = rowptr[node + 1];
    float dd = dinv[node];
    float acc[2] = {0.0f, 0.0f};

    for (int g = beg; g < end; g += 64) {
        int cnt = end - g;
        if (cnt > 64) cnt = 64;
        int myi = node;
        float myw = 0.0f;
        if (lane < cnt) {
            int s = csr_src[g + lane];
            myi = s;
            myw = dinv[s];
        }
        if (F == 128)
            gath128(h16, lane, myi, myw, cnt, acc);
        else
            gath64(h16, lane, myi, myw, cnt, acc);
    }
    if (F == 128) {
        uint32 sv = h16[(size_t)node * 64 + lane];
        acc[0] = fmaf(dd, lo16(sv), acc[0]);
        acc[1] = fmaf(dd, hi16(sv), acc[1]);
        int c = lane * 2;
        float2 r;
        r.x = fmaxf(fmaf(acc[0], dd, b[c]), 0.0f);
        r.y = fmaxf(fmaf(acc[1], dd, b[c + 1]), 0.0f);
        *(float2*)&out[(size_t)node * 128 + c] = r;
    } else {
        acc[0] += __shfl_xor(acc[0], 32);
        acc[1] += __shfl_xor(acc[1], 32);
        if (lane < 32) {
            uint32 sv = h16[(size_t)node * 32 + lane];
            acc[0] = fmaf(dd, lo16(sv), acc[0]);
            acc[1] = fmaf(dd, hi16(sv), acc[1]);
            int c = lane * 2;
            float2 r;
            r.x = fmaxf(fmaf(acc[0], dd, b[c]), 0.0f);
            r.y = fmaxf(fmaf(acc[1], dd, b[c + 1]), 0.0f);
            *(float2*)&out[(size_t)node * 64 + c] = r;
        }
    }
}

// ---------------- GAT per-node attention scalars ----------------
__global__ void k_gat_scalars(const float* __restrict__ hg, const float* __restrict__ a_s,
                              const float* __restrict__ a_d, float* __restrict__ asrc,
                              float* __restrict__ adst, int F) {
    int node = blockIdx.x * (blockDim.x >> 6) + (threadIdx.x >> 6);
    int lane = threadIdx.x & 63;
    if (node >= NN) return;
    float s = 0.0f, d = 0.0f;
    for (int c = lane; c < F; c += 64) {
        float v = hg[(size_t)node * F + c];
        s += v * a_s[c];
        d += v * a_d[c];
    }
    for (int off = 32; off; off >>= 1) {
        s += __shfl_down(s, off);
        d += __shfl_down(d, off);
    }
    if (lane == 0) {
        asrc[node] = s;
        adst[node] = d;
    }
}

// ---------------- GAT gather: one wave per node, fused softmax, bf16 source ----------------
template <int F>
__global__ __launch_bounds__(256) void k_gat_gather_w(const int* __restrict__ rowptr,
                                                      const int* __restrict__ csr_src,
                                                      const uint32* __restrict__ h16,
                                                      const float* __restrict__ asrc,
                                                      const float* __restrict__ adst,
                                                      const float* __restrict__ b,
                                                      float* __restrict__ out) {
    int node = blockIdx.x * 4 + (threadIdx.x >> 6);
    int lane = threadIdx.x & 63;
    int beg = rowptr[node], end = rowptr[node + 1];
    int deg = end - beg;
    float ad = adst[node];
    float slog = lrelu(asrc[node] + ad);
    float acc[2] = {0.0f, 0.0f};
    float wself;

    if (deg <= 64) {
        int myi = node;
        float logit = -1e30f;
        if (lane < deg) {
            myi = csr_src[beg + lane];
            logit = lrelu(asrc[myi] + ad);
        }
        float m = fmaxf(slog, wave_max(logit));
        float e = (lane < deg) ? __expf(logit - m) : 0.0f;
        float z = wave_sum(e) + __expf(slog - m);
        float zi = 1.0f / z;
        float myw = e * zi;
        wself = __expf(slog - m) * zi;
        if (F == 128)
            gath128(h16, lane, myi, myw, deg, acc);
        else
            gath64(h16, lane, myi, myw, deg, acc);
    } else {
        float lm = slog;
        for (int j = beg + lane; j < end; j += 64) lm = fmaxf(lm, lrelu(asrc[csr_src[j]] + ad));
        float m = wave_max(lm);
        float lz = 0.0f;
        for (int j = beg + lane; j < end; j += 64)
            lz += __expf(lrelu(asrc[csr_src[j]] + ad) - m);
        float z = wave_sum(lz) + __expf(slog - m);
        float zi = 1.0f / z;
        wself = __expf(slog - m) * zi;
        for (int g = beg; g < end; g += 64) {
            int cnt = end - g;
            if (cnt > 64) cnt = 64;
            int myi = node;
            float myw = 0.0f;
            if (lane < cnt) {
                int s = csr_src[g + lane];
                myi = s;
                myw = __expf(lrelu(asrc[s] + ad) - m) * zi;
            }
            if (F == 128)
                gath128(h16, lane, myi, myw, cnt, acc);
            else
                gath64(h16, lane, myi, myw, cnt, acc);
        }
    }
    if (F == 128) {
        uint32 sv = h16[(size_t)node * 64 + lane];
        acc[0] = fmaf(wself, lo16(sv), acc[0]);
        acc[1] = fmaf(wself, hi16(sv), acc[1]);
        int c = lane * 2;
        float2 r;
        r.x = acc[0] + b[c];
        r.y = acc[1] + b[c + 1];
        *(float2*)&out[(size_t)node * 128 + c] = r;
    } else {
        acc[0] += __shfl_xor(acc[0], 32);
        acc[1] += __shfl_xor(acc[1], 32);
        if (lane < 32) {
            uint32 sv = h16[(size_t)node * 32 + lane];
            acc[0] = fmaf(wself, lo16(sv), acc[0]);
            acc[1] = fmaf(wself, hi16(sv), acc[1]);
            int c = lane * 2;
            float2 r;
            r.x = acc[0] + b[c];
            r.y = acc[1] + b[c + 1];
            *(float2*)&out[(size_t)node * 64 + c] = r;
        }
    }
}

extern "C" void kernel_launch(void* const* d_in, const int* in_sizes, int n_in,
                              void* d_out, int out_size, void* d_ws, size_t ws_size,
                              hipStream_t stream) {
    const float* x = (const float*)d_in[0];
    const int* src = (const int*)d_in[1];
    const int* dst = src + NE;
    const float* W1 = (const float*)d_in[2];
    const float* b1 = (const float*)d_in[3];
    const float* Wg1 = (const float*)d_in[4];
    const float* ag1s = (const float*)d_in[5];
    const float* ag1d = (const float*)d_in[6];
    const float* bg1 = (const float*)d_in[7];
    const float* W2 = (const float*)d_in[8];
    const float* b2 = (const float*)d_in[9];
    const float* Wg2 = (const float*)d_in[10];
    const float* ag2s = (const float*)d_in[11];
    const float* ag2d = (const float*)d_in[12];
    const float* bg2 = (const float*)d_in[13];

    float* enc = (float*)d_out;             // [NN,128]
    float* dec = enc + (size_t)NN * 128;    // [NN,64]

    float* ws = (float*)d_ws;
    float* bufA = ws;                       // NN*128 fp32 (GEMM out)
    float* bufB = bufA + (size_t)NN * 128;  // NN*128 fp32 (agg out)
    uint32* bufA16 = (uint32*)(bufB + (size_t)NN * 128);  // NN*64 uints (bf16 mirror)
    float* dinv = (float*)(bufA16 + (size_t)NN * 64);     // NN
    float* asrc = dinv + NN;                // NN
    float* adst = asrc + NN;                // NN
    int* cnt = (int*)(adst + NN);           // NN
    int* rowptr = cnt + NN;                 // NN+1
    int* cursor = rowptr + NN + 1;          // NN
    int* csr_src = cursor + NN;             // NE
    int* bsum = csr_src + NE;               // NSB
    int* bofs = bsum + NSB;                 // NSB

    const int TB = 256;
    int gN = (NN + TB - 1) / TB;
    int gE = (NE + TB - 1) / TB;
    int gScal = (NN + 3) / 4;
    int gWave = NN / 4;  // 10000 blocks x 4 waves = 1 wave/node

    // ---- CSR build ----
    k_zero_int<<<gN, TB, 0, stream>>>(cnt, NN);
    k_count<<<gE, TB, 0, stream>>>(dst, cnt);
    k_bsum<<<NSB, 256, 0, stream>>>(cnt, bsum);
    k_scanpart<<<1, 256, 0, stream>>>(bsum, bofs, rowptr);
    k_scatter<<<NSB, 256, 0, stream>>>(cnt, bofs, rowptr, cursor);
    k_fill<<<gE, TB, 0, stream>>>(src, dst, cursor, csr_src);
    k_dinv<<<gN, TB, 0, stream>>>(rowptr, dinv);

    // ---- Layer 1: GCN 128->128 + ReLU -> bufB ----
    k_gemm_t<128, 128><<<dim3(NN / 64, 2), 256, 0, stream>>>(x, W1, bufA, bufA16);
    k_gcn_gather_w<128><<<gWave, 256, 0, stream>>>(rowptr, csr_src, bufA16, dinv, b1, bufB);

    // ---- Layer 2: GAT 128->128 -> encoded ----
    k_gemm_t<128, 128><<<dim3(NN / 64, 2), 256, 0, stream>>>(bufB, Wg1, bufA, bufA16);
    k_gat_scalars<<<gScal, TB, 0, stream>>>(bufA, ag1s, ag1d, asrc, adst, 128);
    k_gat_gather_w<128><<<gWave, 256, 0, stream>>>(rowptr, csr_src, bufA16, asrc, adst, bg1, enc);

    // ---- Layer 3: GCN 128->64 + ReLU -> bufB ----
    k_gemm_t<128, 64><<<dim3(NN / 64, 1), 256, 0, stream>>>(enc, W2, bufA, bufA16);
    k_gcn_gather_w<64><<<gWave, 256, 0, stream>>>(rowptr, csr_src, bufA16, dinv, b2, bufB);

    // ---- Layer 4: GAT 64->64 -> decoded ----
    k_gemm_t<64, 64><<<dim3(NN / 64, 1), 256, 0, stream>>>(bufB, Wg2, bufA, bufA16);
    k_gat_scalars<<<gScal, TB, 0, stream>>>(bufA, ag2s, ag2d, asrc, adst, 64);
    k_gat_gather_w<64><<<gWave, 256, 0, stream>>>(rowptr, csr_src, bufA16, asrc, adst, bg2, dec);
}

// Round 8
// 241.232 us; speedup vs baseline: 3.6108x; 1.0948x over previous
//
#include <hip/hip_runtime.h>

#define NN 40000
#define NE 640000
#define NSB ((NN + 255) / 256)  // 157 scan blocks
#define NNP (NN + 64)           // padded rows for OOB-tolerant mfma A loads

typedef unsigned int uint32;
typedef unsigned short ushort;
typedef __attribute__((ext_vector_type(8))) short bf16x8;
typedef __attribute__((ext_vector_type(4))) float f32x4;

static __device__ __forceinline__ float lrelu(float x) { return x > 0.0f ? x : 0.2f * x; }

static __device__ __forceinline__ float wave_max(float v) {
    for (int off = 32; off; off >>= 1) v = fmaxf(v, __shfl_xor(v, off));
    return v;
}
static __device__ __forceinline__ float wave_sum(float v) {
    for (int off = 32; off; off >>= 1) v += __shfl_xor(v, off);
    return v;
}

// bf16 RNE helpers
static __device__ __forceinline__ uint32 bfr(float x) {
    uint32 u = __float_as_uint(x);
    return u + 0x7FFFu + ((u >> 16) & 1u);
}
static __device__ __forceinline__ ushort bf16of(float x) { return (ushort)(bfr(x) >> 16); }
static __device__ __forceinline__ uint32 pack2(float a, float b) {
    return (bfr(a) >> 16) | (bfr(b) & 0xFFFF0000u);
}
static __device__ __forceinline__ float lo16(uint32 v) { return __uint_as_float(v << 16); }
static __device__ __forceinline__ float hi16(uint32 v) { return __uint_as_float(v & 0xFFFF0000u); }

// ---------------- casts ----------------
__global__ void k_xcast(const float* __restrict__ x, ushort* __restrict__ xb) {
    int i = blockIdx.x * blockDim.x + threadIdx.x;  // 4 elems each
    int base = i * 4;
    if (base < NN * 128) {
        float4 v = *(const float4*)&x[base];
        ushort4 o;
        o.x = bf16of(v.x);
        o.y = bf16of(v.y);
        o.z = bf16of(v.z);
        o.w = bf16of(v.w);
        *(ushort4*)&xb[base] = o;
    }
}
// all 4 weight transposes+casts in one launch: Wt[n*K+k] = bf16(W[k*N+n])
__global__ void k_wcast(const float* __restrict__ W1, const float* __restrict__ Wg1,
                        const float* __restrict__ W2, const float* __restrict__ Wg2,
                        ushort* __restrict__ t1, ushort* __restrict__ tg1,
                        ushort* __restrict__ t2, ushort* __restrict__ tg2) {
    const float* W;
    ushort* T;
    int K, N;
    switch (blockIdx.y) {
        case 0: W = W1; T = t1; K = 128; N = 128; break;
        case 1: W = Wg1; T = tg1; K = 128; N = 128; break;
        case 2: W = W2; T = t2; K = 128; N = 64; break;
        default: W = Wg2; T = tg2; K = 64; N = 64; break;
    }
    int idx = blockIdx.x * 256 + threadIdx.x;
    if (idx < K * N) {
        int n = idx / K, k = idx % K;
        T[idx] = bf16of(W[k * N + n]);
    }
}

// ---------------- MFMA GEMM: Y = X*W, X as bf16 [M][K], W as bf16 Wt[n][k] ----------------
// Block: 128 rows x FOUT cols, 4 waves (wave = 32 rows). No LDS: A/B frags are direct
// 16B global loads (A: 16 rows x 64B coalesced per k-step; B: L2-resident, shared by all blocks).
template <int FIN, int FOUT, bool WF32>
__global__ __launch_bounds__(256) void k_gemm_mfma(const ushort* __restrict__ Xb,
                                                   const ushort* __restrict__ Wt,
                                                   float* __restrict__ Y,
                                                   ushort* __restrict__ Y16) {
    constexpr int NT = FOUT / 16;
    const int w = threadIdx.x >> 6, lane = threadIdx.x & 63;
    const int row0 = blockIdx.x * 128 + w * 32;
    const int lr = lane & 15;
    const int lk = (lane >> 4) * 8;

    f32x4 acc[2][NT];
#pragma unroll
    for (int mt = 0; mt < 2; ++mt)
#pragma unroll
        for (int nt = 0; nt < NT; ++nt) acc[mt][nt] = (f32x4){0.f, 0.f, 0.f, 0.f};

#pragma unroll
    for (int ks = 0; ks < FIN / 32; ++ks) {
        bf16x8 a[2], b[NT];
#pragma unroll
        for (int mt = 0; mt < 2; ++mt)
            a[mt] = *(const bf16x8*)&Xb[(size_t)(row0 + mt * 16 + lr) * FIN + ks * 32 + lk];
#pragma unroll
        for (int nt = 0; nt < NT; ++nt)
            b[nt] = *(const bf16x8*)&Wt[(size_t)(nt * 16 + lr) * FIN + ks * 32 + lk];
#pragma unroll
        for (int mt = 0; mt < 2; ++mt)
#pragma unroll
            for (int nt = 0; nt < NT; ++nt)
                acc[mt][nt] =
                    __builtin_amdgcn_mfma_f32_16x16x32_bf16(a[mt], b[nt], acc[mt][nt], 0, 0, 0);
    }

    const int rbase = (lane >> 4) * 4;
#pragma unroll
    for (int mt = 0; mt < 2; ++mt)
#pragma unroll
        for (int nt = 0; nt < NT; ++nt) {
            int col = nt * 16 + lr;
#pragma unroll
            for (int i = 0; i < 4; ++i) {
                int r = row0 + mt * 16 + rbase + i;
                if (r < NN) {
                    float v = acc[mt][nt][i];
                    if (WF32) Y[(size_t)r * FOUT + col] = v;
                    Y16[(size_t)r * FOUT + col] = bf16of(v);
                }
            }
        }
}

// ---------------- CSR build ----------------
__global__ void k_zero_int(int* __restrict__ p, int n) {
    int i = blockIdx.x * blockDim.x + threadIdx.x;
    if (i < n) p[i] = 0;
}
__global__ void k_count(const int* __restrict__ dst, int* __restrict__ cnt) {
    int e = blockIdx.x * blockDim.x + threadIdx.x;
    if (e < NE) atomicAdd(&cnt[dst[e]], 1);
}
__global__ void k_bsum(const int* __restrict__ cnt, int* __restrict__ bsum) {
    __shared__ int wsums[4];
    int i = blockIdx.x * 256 + threadIdx.x;
    int v = (i < NN) ? cnt[i] : 0;
    for (int off = 32; off; off >>= 1) v += __shfl_down(v, off);
    if ((threadIdx.x & 63) == 0) wsums[threadIdx.x >> 6] = v;
    __syncthreads();
    if (threadIdx.x == 0) bsum[blockIdx.x] = wsums[0] + wsums[1] + wsums[2] + wsums[3];
}
__global__ void k_scanpart(const int* __restrict__ bsum, int* __restrict__ bofs,
                           int* __restrict__ rowptr) {
    __shared__ int s[256];
    int t = threadIdx.x;
    int v = (t < NSB) ? bsum[t] : 0;
    s[t] = v;
    __syncthreads();
    for (int off = 1; off < 256; off <<= 1) {
        int u = (t >= off) ? s[t - off] : 0;
        __syncthreads();
        s[t] += u;
        __syncthreads();
    }
    if (t < NSB) bofs[t] = s[t] - v;
    if (t == 0) rowptr[NN] = NE;
}
// local scan + offsets -> rowptr/cursor; dinv folded in (dinv = rsqrt(1+deg))
__global__ void k_scatter(const int* __restrict__ cnt, const int* __restrict__ bofs,
                          int* __restrict__ rowptr, int* __restrict__ cursor,
                          float* __restrict__ dinv) {
    __shared__ int wsums[4];
    int t = threadIdx.x;
    int lane = t & 63, w = t >> 6;
    int i = blockIdx.x * 256 + t;
    int v = (i < NN) ? cnt[i] : 0;
    int x = v;
    for (int off = 1; off < 64; off <<= 1) {
        int u = __shfl_up(x, off);
        if (lane >= off) x += u;
    }
    if (lane == 63) wsums[w] = x;
    __syncthreads();
    int wofs = 0;
    for (int k = 0; k < w; ++k) wofs += wsums[k];
    int excl = bofs[blockIdx.x] + wofs + x - v;
    if (i < NN) {
        rowptr[i] = excl;
        cursor[i] = excl;
        dinv[i] = rsqrtf(1.0f + (float)v);
    }
}
__global__ void k_fill(const int* __restrict__ src, const int* __restrict__ dst,
                       int* __restrict__ cursor, int* __restrict__ csr_src) {
    int e = blockIdx.x * blockDim.x + threadIdx.x;
    if (e < NE) {
        int p = atomicAdd(&cursor[dst[e]], 1);
        csr_src[p] = src[e];
    }
}

// ---- bf16 gather steps: 8 independent loads in flight, fp32 accumulate ----
static __device__ __forceinline__ void gath128(const uint32* __restrict__ h16, int lane, int myi,
                                               float myw, int cnt, float* acc) {
    for (int j = 0; j < cnt; j += 8) {
        int s[8];
        float w[8];
#pragma unroll
        for (int u = 0; u < 8; ++u) {
            s[u] = __shfl(myi, j + u);
            w[u] = __shfl(myw, j + u);
        }
        uint32 v[8];
#pragma unroll
        for (int u = 0; u < 8; ++u) v[u] = h16[(size_t)s[u] * 64 + lane];
#pragma unroll
        for (int u = 0; u < 8; ++u) {
            acc[0] = fmaf(w[u], lo16(v[u]), acc[0]);
            acc[1] = fmaf(w[u], hi16(v[u]), acc[1]);
        }
    }
}
static __device__ __forceinline__ void gath64(const uint32* __restrict__ h16, int lane, int myi,
                                              float myw, int cnt, float* acc) {
    int hh = lane >> 5, cl = lane & 31;
    for (int j = 0; j < cnt; j += 16) {
        int s[8];
        float w[8];
#pragma unroll
        for (int u = 0; u < 8; ++u) {
            int e = j + 2 * u + hh;
            s[u] = __shfl(myi, e);
            w[u] = __shfl(myw, e);
        }
        uint32 v[8];
#pragma unroll
        for (int u = 0; u < 8; ++u) v[u] = h16[(size_t)s[u] * 32 + cl];
#pragma unroll
        for (int u = 0; u < 8; ++u) {
            acc[0] = fmaf(w[u], lo16(v[u]), acc[0]);
            acc[1] = fmaf(w[u], hi16(v[u]), acc[1]);
        }
    }
}

// ---------------- GCN gather: one wave per node, bf16 in, bf16 out ----------------
template <int F>
__global__ __launch_bounds__(256) void k_gcn_gather_w(const int* __restrict__ rowptr,
                                                      const int* __restrict__ csr_src,
                                                      const uint32* __restrict__ h16,
                                                      const float* __restrict__ dinv,
                                                      const float* __restrict__ b,
                                                      uint32* __restrict__ out16) {
    int node = blockIdx.x * 4 + (threadIdx.x >> 6);
    int lane = threadIdx.x & 63;
    int beg = rowptr[node], end = rowptr[node + 1];
    float dd = dinv[node];
    float acc[2] = {0.0f, 0.0f};

    for (int g = beg; g < end; g += 64) {
        int cnt = end - g;
        if (cnt > 64) cnt = 64;
        int myi = node;
        float myw = 0.0f;
        if (lane < cnt) {
            int s = csr_src[g + lane];
            myi = s;
            myw = dinv[s];
        }
        if (F == 128)
            gath128(h16, lane, myi, myw, cnt, acc);
        else
            gath64(h16, lane, myi, myw, cnt, acc);
    }
    if (F == 128) {
        uint32 sv = h16[(size_t)node * 64 + lane];
        acc[0] = fmaf(dd, lo16(sv), acc[0]);
        acc[1] = fmaf(dd, hi16(sv), acc[1]);
        int c = lane * 2;
        float rx = fmaxf(fmaf(acc[0], dd, b[c]), 0.0f);
        float ry = fmaxf(fmaf(acc[1], dd, b[c + 1]), 0.0f);
        out16[(size_t)node * 64 + lane] = pack2(rx, ry);
    } else {
        acc[0] += __shfl_xor(acc[0], 32);
        acc[1] += __shfl_xor(acc[1], 32);
        if (lane < 32) {
            uint32 sv = h16[(size_t)node * 32 + lane];
            acc[0] = fmaf(dd, lo16(sv), acc[0]);
            acc[1] = fmaf(dd, hi16(sv), acc[1]);
            int c = lane * 2;
            float rx = fmaxf(fmaf(acc[0], dd, b[c]), 0.0f);
            float ry = fmaxf(fmaf(acc[1], dd, b[c + 1]), 0.0f);
            out16[(size_t)node * 32 + lane] = pack2(rx, ry);
        }
    }
}

// ---------------- GAT per-node attention scalars (fp32 input) ----------------
__global__ void k_gat_scalars(const float* __restrict__ hg, const float* __restrict__ a_s,
                              const float* __restrict__ a_d, float* __restrict__ asrc,
                              float* __restrict__ adst, int F) {
    int node = blockIdx.x * (blockDim.x >> 6) + (threadIdx.x >> 6);
    int lane = threadIdx.x & 63;
    if (node >= NN) return;
    float s = 0.0f, d = 0.0f;
    for (int c = lane; c < F; c += 64) {
        float v = hg[(size_t)node * F + c];
        s += v * a_s[c];
        d += v * a_d[c];
    }
    for (int off = 32; off; off >>= 1) {
        s += __shfl_down(s, off);
        d += __shfl_down(d, off);
    }
    if (lane == 0) {
        asrc[node] = s;
        adst[node] = d;
    }
}

// ---------------- GAT gather: fused softmax, bf16 in, fp32 out (+opt bf16 mirror) -------------
template <int F, bool WB16>
__global__ __launch_bounds__(256) void k_gat_gather_w(const int* __restrict__ rowptr,
                                                      const int* __restrict__ csr_src,
                                                      const uint32* __restrict__ h16,
                                                      const float* __restrict__ asrc,
                                                      const float* __restrict__ adst,
                                                      const float* __restrict__ b,
                                                      float* __restrict__ out,
                                                      uint32* __restrict__ out16) {
    int node = blockIdx.x * 4 + (threadIdx.x >> 6);
    int lane = threadIdx.x & 63;
    int beg = rowptr[node], end = rowptr[node + 1];
    int deg = end - beg;
    float ad = adst[node];
    float slog = lrelu(asrc[node] + ad);
    float acc[2] = {0.0f, 0.0f};
    float wself;

    if (deg <= 64) {
        int myi = node;
        float logit = -1e30f;
        if (lane < deg) {
            myi = csr_src[beg + lane];
            logit = lrelu(asrc[myi] + ad);
        }
        float m = fmaxf(slog, wave_max(logit));
        float e = (lane < deg) ? __expf(logit - m) : 0.0f;
        float z = wave_sum(e) + __expf(slog - m);
        float zi = 1.0f / z;
        float myw = e * zi;
        wself = __expf(slog - m) * zi;
        if (F == 128)
            gath128(h16, lane, myi, myw, deg, acc);
        else
            gath64(h16, lane, myi, myw, deg, acc);
    } else {
        float lm = slog;
        for (int j = beg + lane; j < end; j += 64) lm = fmaxf(lm, lrelu(asrc[csr_src[j]] + ad));
        float m = wave_max(lm);
        float lz = 0.0f;
        for (int j = beg + lane; j < end; j += 64)
            lz += __expf(lrelu(asrc[csr_src[j]] + ad) - m);
        float z = wave_sum(lz) + __expf(slog - m);
        float zi = 1.0f / z;
        wself = __expf(slog - m) * zi;
        for (int g = beg; g < end; g += 64) {
            int cnt = end - g;
            if (cnt > 64) cnt = 64;
            int myi = node;
            float myw = 0.0f;
            if (lane < cnt) {
                int s = csr_src[g + lane];
                myi = s;
                myw = __expf(lrelu(asrc[s] + ad) - m) * zi;
            }
            if (F == 128)
                gath128(h16, lane, myi, myw, cnt, acc);
            else
                gath64(h16, lane, myi, myw, cnt, acc);
        }
    }
    if (F == 128) {
        uint32 sv = h16[(size_t)node * 64 + lane];
        acc[0] = fmaf(wself, lo16(sv), acc[0]);
        acc[1] = fmaf(wself, hi16(sv), acc[1]);
        int c = lane * 2;
        float2 r;
        r.x = acc[0] + b[c];
        r.y = acc[1] + b[c + 1];
        *(float2*)&out[(size_t)node * 128 + c] = r;
        if (WB16) out16[(size_t)node * 64 + lane] = pack2(r.x, r.y);
    } else {
        acc[0] += __shfl_xor(acc[0], 32);
        acc[1] += __shfl_xor(acc[1], 32);
        if (lane < 32) {
            uint32 sv = h16[(size_t)node * 32 + lane];
            acc[0] = fmaf(wself, lo16(sv), acc[0]);
            acc[1] = fmaf(wself, hi16(sv), acc[1]);
            int c = lane * 2;
            float2 r;
            r.x = acc[0] + b[c];
            r.y = acc[1] + b[c + 1];
            *(float2*)&out[(size_t)node * 64 + c] = r;
            if (WB16) out16[(size_t)node * 32 + lane] = pack2(r.x, r.y);
        }
    }
}

extern "C" void kernel_launch(void* const* d_in, const int* in_sizes, int n_in,
                              void* d_out, int out_size, void* d_ws, size_t ws_size,
                              hipStream_t stream) {
    const float* x = (const float*)d_in[0];
    const int* src = (const int*)d_in[1];
    const int* dst = src + NE;
    const float* W1 = (const float*)d_in[2];
    const float* b1 = (const float*)d_in[3];
    const float* Wg1 = (const float*)d_in[4];
    const float* ag1s = (const float*)d_in[5];
    const float* ag1d = (const float*)d_in[6];
    const float* bg1 = (const float*)d_in[7];
    const float* W2 = (const float*)d_in[8];
    const float* b2 = (const float*)d_in[9];
    const float* Wg2 = (const float*)d_in[10];
    const float* ag2s = (const float*)d_in[11];
    const float* ag2d = (const float*)d_in[12];
    const float* bg2 = (const float*)d_in[13];

    float* enc = (float*)d_out;           // [NN,128]
    float* dec = enc + (size_t)NN * 128;  // [NN,64]

    // workspace layout
    float* bufA = (float*)d_ws;  // NN*128 fp32 (GEMM out for GAT layers)
    ushort* ush = (ushort*)(bufA + (size_t)NN * 128);
    ushort* m0 = ush;                          // NNP*128 (xb, later enc16)
    ushort* m1 = m0 + (size_t)NNP * 128;       // NNP*128 (GCN gather out)
    ushort* m2 = m1 + (size_t)NNP * 128;       // NNP*128 (GEMM out mirror)
    ushort* wt1 = m2 + (size_t)NNP * 128;      // 128*128
    ushort* wtg1 = wt1 + 128 * 128;            // 128*128
    ushort* wt2 = wtg1 + 128 * 128;            // 64*128
    ushort* wtg2 = wt2 + 64 * 128;             // 64*64
    float* dinv = (float*)(wtg2 + 64 * 64);    // NN
    float* asrc = dinv + NN;                   // NN
    float* adst = asrc + NN;                   // NN
    int* cnt = (int*)(adst + NN);              // NN
    int* rowptr = cnt + NN;                    // NN+1
    int* cursor = rowptr + NN + 1;             // NN
    int* csr_src = cursor + NN;                // NE
    int* bsum = csr_src + NE;                  // NSB
    int* bofs = bsum + NSB;                    // NSB

    const int TB = 256;
    int gN = (NN + TB - 1) / TB;
    int gE = (NE + TB - 1) / TB;
    int gScal = (NN + 3) / 4;
    int gWave = NN / 4;
    int gM = (NN + 127) / 128;  // 313 mfma-gemm blocks

    // ---- casts ----
    k_xcast<<<(NN * 128 / 4 + TB - 1) / TB, TB, 0, stream>>>(x, m0);
    k_wcast<<<dim3(64, 4), TB, 0, stream>>>(W1, Wg1, W2, Wg2, wt1, wtg1, wt2, wtg2);

    // ---- CSR build ----
    k_zero_int<<<gN, TB, 0, stream>>>(cnt, NN);
    k_count<<<gE, TB, 0, stream>>>(dst, cnt);
    k_bsum<<<NSB, 256, 0, stream>>>(cnt, bsum);
    k_scanpart<<<1, 256, 0, stream>>>(bsum, bofs, rowptr);
    k_scatter<<<NSB, 256, 0, stream>>>(cnt, bofs, rowptr, cursor, dinv);
    k_fill<<<gE, TB, 0, stream>>>(src, dst, cursor, csr_src);

    // ---- Layer 1: GCN 128->128 + ReLU ----
    k_gemm_mfma<128, 128, false><<<gM, 256, 0, stream>>>(m0, wt1, bufA, m2);
    k_gcn_gather_w<128><<<gWave, 256, 0, stream>>>(rowptr, csr_src, (uint32*)m2, dinv, b1,
                                                   (uint32*)m1);

    // ---- Layer 2: GAT 128->128 -> encoded (fp32) + enc16 mirror (m0) ----
    k_gemm_mfma<128, 128, true><<<gM, 256, 0, stream>>>(m1, wtg1, bufA, m2);
    k_gat_scalars<<<gScal, TB, 0, stream>>>(bufA, ag1s, ag1d, asrc, adst, 128);
    k_gat_gather_w<128, true><<<gWave, 256, 0, stream>>>(rowptr, csr_src, (uint32*)m2, asrc,
                                                         adst, bg1, enc, (uint32*)m0);

    // ---- Layer 3: GCN 128->64 + ReLU ----
    k_gemm_mfma<128, 64, false><<<gM, 256, 0, stream>>>(m0, wt2, bufA, m2);
    k_gcn_gather_w<64><<<gWave, 256, 0, stream>>>(rowptr, csr_src, (uint32*)m2, dinv, b2,
                                                  (uint32*)m1);

    // ---- Layer 4: GAT 64->64 -> decoded (fp32) ----
    k_gemm_mfma<64, 64, true><<<gM, 256, 0, stream>>>(m1, wtg2, bufA, m2);
    k_gat_scalars<<<gScal, TB, 0, stream>>>(bufA, ag2s, ag2d, asrc, adst, 64);
    k_gat_gather_w<64, false><<<gWave, 256, 0, stream>>>(rowptr, csr_src, (uint32*)m2, asrc,
                                                         adst, bg2, dec, (uint32*)m0);
}

// Round 9
// 235.215 us; speedup vs baseline: 3.7032x; 1.0256x over previous
//
#include <hip/hip_runtime.h>

#define NN 40000
#define NE 640000
#define NSB ((NN + 255) / 256)  // 157 scan blocks
#define NNP (NN + 64)           // padded rows for OOB-tolerant mfma A loads

typedef unsigned int uint32;
typedef unsigned short ushort;
typedef __attribute__((ext_vector_type(8))) short bf16x8;
typedef __attribute__((ext_vector_type(4))) float f32x4;

static __device__ __forceinline__ float lrelu(float x) { return x > 0.0f ? x : 0.2f * x; }

static __device__ __forceinline__ float wave_max(float v) {
    for (int off = 32; off; off >>= 1) v = fmaxf(v, __shfl_xor(v, off));
    return v;
}
static __device__ __forceinline__ float wave_sum(float v) {
    for (int off = 32; off; off >>= 1) v += __shfl_xor(v, off);
    return v;
}

// bf16 RNE helpers
static __device__ __forceinline__ uint32 bfr(float x) {
    uint32 u = __float_as_uint(x);
    return u + 0x7FFFu + ((u >> 16) & 1u);
}
static __device__ __forceinline__ ushort bf16of(float x) { return (ushort)(bfr(x) >> 16); }
static __device__ __forceinline__ uint32 pack2(float a, float b) {
    return (bfr(a) >> 16) | (bfr(b) & 0xFFFF0000u);
}
static __device__ __forceinline__ float lo16(uint32 v) { return __uint_as_float(v << 16); }
static __device__ __forceinline__ float hi16(uint32 v) { return __uint_as_float(v & 0xFFFF0000u); }

// ---------------- fused casts: x -> bf16 (y=0), 4 weight transpose-casts (y=1..4) ----------------
__global__ void k_cast(const float* __restrict__ x, ushort* __restrict__ xb,
                       const float* __restrict__ W1, const float* __restrict__ Wg1,
                       const float* __restrict__ W2, const float* __restrict__ Wg2,
                       ushort* __restrict__ t1, ushort* __restrict__ tg1,
                       ushort* __restrict__ t2, ushort* __restrict__ tg2) {
    if (blockIdx.y == 0) {
        int base = (blockIdx.x * 256 + threadIdx.x) * 4;
        if (base < NN * 128) {
            float4 v = *(const float4*)&x[base];
            ushort4 o;
            o.x = bf16of(v.x);
            o.y = bf16of(v.y);
            o.z = bf16of(v.z);
            o.w = bf16of(v.w);
            *(ushort4*)&xb[base] = o;
        }
        return;
    }
    const float* W;
    ushort* T;
    int K, N;
    switch (blockIdx.y) {
        case 1: W = W1; T = t1; K = 128; N = 128; break;
        case 2: W = Wg1; T = tg1; K = 128; N = 128; break;
        case 3: W = W2; T = t2; K = 128; N = 64; break;
        default: W = Wg2; T = tg2; K = 64; N = 64; break;
    }
    int idx = blockIdx.x * 256 + threadIdx.x;
    if (idx < K * N) {
        int n = idx / K, k = idx % K;
        T[idx] = bf16of(W[k * N + n]);
    }
}

// ---------------- MFMA GEMM: Y16 = bf16(X*W); GAT: fused asrc/adst epilogue ----------------
// Block: 128 rows x FOUT cols, 4 waves (wave = 32 rows). No LDS: A/B frags are direct
// 16B global loads (A: 16 rows x 64B coalesced per k-step; B: L2-resident, shared by all blocks).
template <int FIN, int FOUT, bool GAT>
__global__ __launch_bounds__(256) void k_gemm_mfma(const ushort* __restrict__ Xb,
                                                   const ushort* __restrict__ Wt,
                                                   ushort* __restrict__ Y16,
                                                   const float* __restrict__ a_s,
                                                   const float* __restrict__ a_d,
                                                   float* __restrict__ asrc,
                                                   float* __restrict__ adst) {
    constexpr int NT = FOUT / 16;
    const int w = threadIdx.x >> 6, lane = threadIdx.x & 63;
    const int row0 = blockIdx.x * 128 + w * 32;
    const int lr = lane & 15;
    const int lk = (lane >> 4) * 8;

    f32x4 acc[2][NT];
#pragma unroll
    for (int mt = 0; mt < 2; ++mt)
#pragma unroll
        for (int nt = 0; nt < NT; ++nt) acc[mt][nt] = (f32x4){0.f, 0.f, 0.f, 0.f};

#pragma unroll
    for (int ks = 0; ks < FIN / 32; ++ks) {
        bf16x8 a[2], b[NT];
#pragma unroll
        for (int mt = 0; mt < 2; ++mt)
            a[mt] = *(const bf16x8*)&Xb[(size_t)(row0 + mt * 16 + lr) * FIN + ks * 32 + lk];
#pragma unroll
        for (int nt = 0; nt < NT; ++nt)
            b[nt] = *(const bf16x8*)&Wt[(size_t)(nt * 16 + lr) * FIN + ks * 32 + lk];
#pragma unroll
        for (int mt = 0; mt < 2; ++mt)
#pragma unroll
            for (int nt = 0; nt < NT; ++nt)
                acc[mt][nt] =
                    __builtin_amdgcn_mfma_f32_16x16x32_bf16(a[mt], b[nt], acc[mt][nt], 0, 0, 0);
    }

    const int rbase = (lane >> 4) * 4;
#pragma unroll
    for (int mt = 0; mt < 2; ++mt)
#pragma unroll
        for (int nt = 0; nt < NT; ++nt) {
            int col = nt * 16 + lr;
#pragma unroll
            for (int i = 0; i < 4; ++i) {
                int r = row0 + mt * 16 + rbase + i;
                if (r < NN) Y16[(size_t)r * FOUT + col] = bf16of(acc[mt][nt][i]);
            }
        }

    if (GAT) {
        // per-row dot with a_src/a_dst from fp32 accumulators; reduce across the 16-lane col group
#pragma unroll
        for (int mt = 0; mt < 2; ++mt)
#pragma unroll
            for (int i = 0; i < 4; ++i) {
                float ss = 0.0f, dd = 0.0f;
#pragma unroll
                for (int nt = 0; nt < NT; ++nt) {
                    float v = acc[mt][nt][i];
                    ss = fmaf(v, a_s[nt * 16 + lr], ss);
                    dd = fmaf(v, a_d[nt * 16 + lr], dd);
                }
#pragma unroll
                for (int off = 1; off < 16; off <<= 1) {
                    ss += __shfl_xor(ss, off);
                    dd += __shfl_xor(dd, off);
                }
                if (lr == 0) {
                    int r = row0 + mt * 16 + rbase + i;
                    if (r < NN) {
                        asrc[r] = ss;
                        adst[r] = dd;
                    }
                }
            }
    }
}

// ---------------- CSR build ----------------
__global__ void k_zero_int(int* __restrict__ p, int n) {
    int i = blockIdx.x * blockDim.x + threadIdx.x;
    if (i < n) p[i] = 0;
}
__global__ void k_count(const int* __restrict__ dst, int* __restrict__ cnt) {
    int e = blockIdx.x * blockDim.x + threadIdx.x;
    if (e < NE) atomicAdd(&cnt[dst[e]], 1);
}
__global__ void k_bsum(const int* __restrict__ cnt, int* __restrict__ bsum) {
    __shared__ int wsums[4];
    int i = blockIdx.x * 256 + threadIdx.x;
    int v = (i < NN) ? cnt[i] : 0;
    for (int off = 32; off; off >>= 1) v += __shfl_down(v, off);
    if ((threadIdx.x & 63) == 0) wsums[threadIdx.x >> 6] = v;
    __syncthreads();
    if (threadIdx.x == 0) bsum[blockIdx.x] = wsums[0] + wsums[1] + wsums[2] + wsums[3];
}
__global__ void k_scanpart(const int* __restrict__ bsum, int* __restrict__ bofs,
                           int* __restrict__ rowptr) {
    __shared__ int s[256];
    int t = threadIdx.x;
    int v = (t < NSB) ? bsum[t] : 0;
    s[t] = v;
    __syncthreads();
    for (int off = 1; off < 256; off <<= 1) {
        int u = (t >= off) ? s[t - off] : 0;
        __syncthreads();
        s[t] += u;
        __syncthreads();
    }
    if (t < NSB) bofs[t] = s[t] - v;
    if (t == 0) rowptr[NN] = NE;
}
__global__ void k_scatter(const int* __restrict__ cnt, const int* __restrict__ bofs,
                          int* __restrict__ rowptr, int* __restrict__ cursor,
                          float* __restrict__ dinv) {
    __shared__ int wsums[4];
    int t = threadIdx.x;
    int lane = t & 63, w = t >> 6;
    int i = blockIdx.x * 256 + t;
    int v = (i < NN) ? cnt[i] : 0;
    int x = v;
    for (int off = 1; off < 64; off <<= 1) {
        int u = __shfl_up(x, off);
        if (lane >= off) x += u;
    }
    if (lane == 63) wsums[w] = x;
    __syncthreads();
    int wofs = 0;
    for (int k = 0; k < w; ++k) wofs += wsums[k];
    int excl = bofs[blockIdx.x] + wofs + x - v;
    if (i < NN) {
        rowptr[i] = excl;
        cursor[i] = excl;
        dinv[i] = rsqrtf(1.0f + (float)v);
    }
}
__global__ void k_fill(const int* __restrict__ src, const int* __restrict__ dst,
                       int* __restrict__ cursor, int* __restrict__ csr_src) {
    int e = blockIdx.x * blockDim.x + threadIdx.x;
    if (e < NE) {
        int p = atomicAdd(&cursor[dst[e]], 1);
        csr_src[p] = src[e];
    }
}

// ---- bf16 gather steps: 8 independent loads in flight, fp32 accumulate ----
static __device__ __forceinline__ void gath128(const uint32* __restrict__ h16, int lane, int myi,
                                               float myw, int cnt, float* acc) {
    for (int j = 0; j < cnt; j += 8) {
        int s[8];
        float w[8];
#pragma unroll
        for (int u = 0; u < 8; ++u) {
            s[u] = __shfl(myi, j + u);
            w[u] = __shfl(myw, j + u);
        }
        uint32 v[8];
#pragma unroll
        for (int u = 0; u < 8; ++u) v[u] = h16[(size_t)s[u] * 64 + lane];
#pragma unroll
        for (int u = 0; u < 8; ++u) {
            acc[0] = fmaf(w[u], lo16(v[u]), acc[0]);
            acc[1] = fmaf(w[u], hi16(v[u]), acc[1]);
        }
    }
}
static __device__ __forceinline__ void gath64(const uint32* __restrict__ h16, int lane, int myi,
                                              float myw, int cnt, float* acc) {
    int hh = lane >> 5, cl = lane & 31;
    for (int j = 0; j < cnt; j += 16) {
        int s[8];
        float w[8];
#pragma unroll
        for (int u = 0; u < 8; ++u) {
            int e = j + 2 * u + hh;
            s[u] = __shfl(myi, e);
            w[u] = __shfl(myw, e);
        }
        uint32 v[8];
#pragma unroll
        for (int u = 0; u < 8; ++u) v[u] = h16[(size_t)s[u] * 32 + cl];
#pragma unroll
        for (int u = 0; u < 8; ++u) {
            acc[0] = fmaf(w[u], lo16(v[u]), acc[0]);
            acc[1] = fmaf(w[u], hi16(v[u]), acc[1]);
        }
    }
}

// ---------------- GCN gather: one wave per node, bf16 in, bf16 out ----------------
template <int F>
__global__ __launch_bounds__(256) void k_gcn_gather_w(const int* __restrict__ rowptr,
                                                      const int* __restrict__ csr_src,
                                                      const uint32* __restrict__ h16,
                                                      const float* __restrict__ dinv,
                                                      const float* __restrict__ b,
                                                      uint32* __restrict__ out16) {
    int node = blockIdx.x * 4 + (threadIdx.x >> 6);
    int lane = threadIdx.x & 63;
    int beg = rowptr[node], end = rowptr[node + 1];
    float dd = dinv[node];
    float acc[2] = {0.0f, 0.0f};

    for (int g = beg; g < end; g += 64) {
        int cnt = end - g;
        if (cnt > 64) cnt = 64;
        int myi = node;
        float myw = 0.0f;
        if (lane < cnt) {
            int s = __builtin_nontemporal_load(&csr_src[g + lane]);
            myi = s;
            myw = dinv[s];
        }
        if (F == 128)
            gath128(h16, lane, myi, myw, cnt, acc);
        else
            gath64(h16, lane, myi, myw, cnt, acc);
    }
    if (F == 128) {
        uint32 sv = h16[(size_t)node * 64 + lane];
        acc[0] = fmaf(dd, lo16(sv), acc[0]);
        acc[1] = fmaf(dd, hi16(sv), acc[1]);
        int c = lane * 2;
        float rx = fmaxf(fmaf(acc[0], dd, b[c]), 0.0f);
        float ry = fmaxf(fmaf(acc[1], dd, b[c + 1]), 0.0f);
        out16[(size_t)node * 64 + lane] = pack2(rx, ry);
    } else {
        acc[0] += __shfl_xor(acc[0], 32);
        acc[1] += __shfl_xor(acc[1], 32);
        if (lane < 32) {
            uint32 sv = h16[(size_t)node * 32 + lane];
            acc[0] = fmaf(dd, lo16(sv), acc[0]);
            acc[1] = fmaf(dd, hi16(sv), acc[1]);
            int c = lane * 2;
            float rx = fmaxf(fmaf(acc[0], dd, b[c]), 0.0f);
            float ry = fmaxf(fmaf(acc[1], dd, b[c + 1]), 0.0f);
            out16[(size_t)node * 32 + lane] = pack2(rx, ry);
        }
    }
}

// ---------------- GAT gather: fused softmax, bf16 in, fp32 out (+opt bf16 mirror) -------------
template <int F, bool WB16>
__global__ __launch_bounds__(256) void k_gat_gather_w(const int* __restrict__ rowptr,
                                                      const int* __restrict__ csr_src,
                                                      const uint32* __restrict__ h16,
                                                      const float* __restrict__ asrc,
                                                      const float* __restrict__ adst,
                                                      const float* __restrict__ b,
                                                      float* __restrict__ out,
                                                      uint32* __restrict__ out16) {
    int node = blockIdx.x * 4 + (threadIdx.x >> 6);
    int lane = threadIdx.x & 63;
    int beg = rowptr[node], end = rowptr[node + 1];
    int deg = end - beg;
    float ad = adst[node];
    float slog = lrelu(asrc[node] + ad);
    float acc[2] = {0.0f, 0.0f};
    float wself;

    if (deg <= 64) {
        int myi = node;
        float logit = -1e30f;
        if (lane < deg) {
            myi = __builtin_nontemporal_load(&csr_src[beg + lane]);
            logit = lrelu(asrc[myi] + ad);
        }
        float m = fmaxf(slog, wave_max(logit));
        float e = (lane < deg) ? __expf(logit - m) : 0.0f;
        float z = wave_sum(e) + __expf(slog - m);
        float zi = 1.0f / z;
        float myw = e * zi;
        wself = __expf(slog - m) * zi;
        if (F == 128)
            gath128(h16, lane, myi, myw, deg, acc);
        else
            gath64(h16, lane, myi, myw, deg, acc);
    } else {
        float lm = slog;
        for (int j = beg + lane; j < end; j += 64) lm = fmaxf(lm, lrelu(asrc[csr_src[j]] + ad));
        float m = wave_max(lm);
        float lz = 0.0f;
        for (int j = beg + lane; j < end; j += 64)
            lz += __expf(lrelu(asrc[csr_src[j]] + ad) - m);
        float z = wave_sum(lz) + __expf(slog - m);
        float zi = 1.0f / z;
        wself = __expf(slog - m) * zi;
        for (int g = beg; g < end; g += 64) {
            int cnt = end - g;
            if (cnt > 64) cnt = 64;
            int myi = node;
            float myw = 0.0f;
            if (lane < cnt) {
                int s = csr_src[g + lane];
                myi = s;
                myw = __expf(lrelu(asrc[s] + ad) - m) * zi;
            }
            if (F == 128)
                gath128(h16, lane, myi, myw, cnt, acc);
            else
                gath64(h16, lane, myi, myw, cnt, acc);
        }
    }
    if (F == 128) {
        uint32 sv = h16[(size_t)node * 64 + lane];
        acc[0] = fmaf(wself, lo16(sv), acc[0]);
        acc[1] = fmaf(wself, hi16(sv), acc[1]);
        int c = lane * 2;
        float2 r;
        r.x = acc[0] + b[c];
        r.y = acc[1] + b[c + 1];
        *(float2*)&out[(size_t)node * 128 + c] = r;
        if (WB16) out16[(size_t)node * 64 + lane] = pack2(r.x, r.y);
    } else {
        acc[0] += __shfl_xor(acc[0], 32);
        acc[1] += __shfl_xor(acc[1], 32);
        if (lane < 32) {
            uint32 sv = h16[(size_t)node * 32 + lane];
            acc[0] = fmaf(wself, lo16(sv), acc[0]);
            acc[1] = fmaf(wself, hi16(sv), acc[1]);
            int c = lane * 2;
            float2 r;
            r.x = acc[0] + b[c];
            r.y = acc[1] + b[c + 1];
            *(float2*)&out[(size_t)node * 64 + c] = r;
            if (WB16) out16[(size_t)node * 32 + lane] = pack2(r.x, r.y);
        }
    }
}

extern "C" void kernel_launch(void* const* d_in, const int* in_sizes, int n_in,
                              void* d_out, int out_size, void* d_ws, size_t ws_size,
                              hipStream_t stream) {
    const float* x = (const float*)d_in[0];
    const int* src = (const int*)d_in[1];
    const int* dst = src + NE;
    const float* W1 = (const float*)d_in[2];
    const float* b1 = (const float*)d_in[3];
    const float* Wg1 = (const float*)d_in[4];
    const float* ag1s = (const float*)d_in[5];
    const float* ag1d = (const float*)d_in[6];
    const float* bg1 = (const float*)d_in[7];
    const float* W2 = (const float*)d_in[8];
    const float* b2 = (const float*)d_in[9];
    const float* Wg2 = (const float*)d_in[10];
    const float* ag2s = (const float*)d_in[11];
    const float* ag2d = (const float*)d_in[12];
    const float* bg2 = (const float*)d_in[13];

    float* enc = (float*)d_out;           // [NN,128]
    float* dec = enc + (size_t)NN * 128;  // [NN,64]

    // workspace layout (all bf16 mirrors padded to NNP rows)
    ushort* m0 = (ushort*)d_ws;                // NNP*128 (xb, later enc16)
    ushort* m1 = m0 + (size_t)NNP * 128;       // NNP*128 (GCN gather out)
    ushort* m2 = m1 + (size_t)NNP * 128;       // NNP*128 (GEMM out mirror)
    ushort* wt1 = m2 + (size_t)NNP * 128;      // 128*128
    ushort* wtg1 = wt1 + 128 * 128;            // 128*128
    ushort* wt2 = wtg1 + 128 * 128;            // 64*128
    ushort* wtg2 = wt2 + 64 * 128;             // 64*64
    float* dinv = (float*)(wtg2 + 64 * 64);    // NN
    float* asrc = dinv + NN;                   // NN
    float* adst = asrc + NN;                   // NN
    int* cnt = (int*)(adst + NN);              // NN
    int* rowptr = cnt + NN;                    // NN+1
    int* cursor = rowptr + NN + 1;             // NN
    int* csr_src = cursor + NN;                // NE
    int* bsum = csr_src + NE;                  // NSB
    int* bofs = bsum + NSB;                    // NSB

    const int TB = 256;
    int gN = (NN + TB - 1) / TB;
    int gE = (NE + TB - 1) / TB;
    int gWave = NN / 4;
    int gM = (NN + 127) / 128;  // 313 mfma-gemm blocks

    // ---- fused casts (x + 4 weights) ----
    k_cast<<<dim3((NN * 128 / 4 + TB - 1) / TB, 5), TB, 0, stream>>>(x, m0, W1, Wg1, W2, Wg2,
                                                                     wt1, wtg1, wt2, wtg2);

    // ---- CSR build ----
    k_zero_int<<<gN, TB, 0, stream>>>(cnt, NN);
    k_count<<<gE, TB, 0, stream>>>(dst, cnt);
    k_bsum<<<NSB, 256, 0, stream>>>(cnt, bsum);
    k_scanpart<<<1, 256, 0, stream>>>(bsum, bofs, rowptr);
    k_scatter<<<NSB, 256, 0, stream>>>(cnt, bofs, rowptr, cursor, dinv);
    k_fill<<<gE, TB, 0, stream>>>(src, dst, cursor, csr_src);

    // ---- Layer 1: GCN 128->128 + ReLU ----
    k_gemm_mfma<128, 128, false><<<gM, 256, 0, stream>>>(m0, wt1, m2, nullptr, nullptr, nullptr,
                                                         nullptr);
    k_gcn_gather_w<128><<<gWave, 256, 0, stream>>>(rowptr, csr_src, (uint32*)m2, dinv, b1,
                                                   (uint32*)m1);

    // ---- Layer 2: GAT 128->128 -> encoded (fp32) + enc16 mirror (m0) ----
    k_gemm_mfma<128, 128, true><<<gM, 256, 0, stream>>>(m1, wtg1, m2, ag1s, ag1d, asrc, adst);
    k_gat_gather_w<128, true><<<gWave, 256, 0, stream>>>(rowptr, csr_src, (uint32*)m2, asrc,
                                                         adst, bg1, enc, (uint32*)m0);

    // ---- Layer 3: GCN 128->64 + ReLU ----
    k_gemm_mfma<128, 64, false><<<gM, 256, 0, stream>>>(m0, wt2, m2, nullptr, nullptr, nullptr,
                                                        nullptr);
    k_gcn_gather_w<64><<<gWave, 256, 0, stream>>>(rowptr, csr_src, (uint32*)m2, dinv, b2,
                                                  (uint32*)m1);

    // ---- Layer 4: GAT 64->64 -> decoded (fp32) ----
    k_gemm_mfma<64, 64, true><<<gM, 256, 0, stream>>>(m1, wtg2, m2, ag2s, ag2d, asrc, adst);
    k_gat_gather_w<64, false><<<gWave, 256, 0, stream>>>(rowptr, csr_src, (uint32*)m2, asrc,
                                                         adst, bg2, dec, (uint32*)m0);
}